// Round 2
// baseline (924.405 us; speedup 1.0000x reference)
//
#include <hip/hip_runtime.h>
#include <hip/hip_bf16.h>

// Problem constants
#define B_  1024
#define L_  2
#define D_  1024
#define F_  32768
#define K1  (L_*D_)      // 2048 — encoder K
#define M_  B_           // 1024
#define N2  (L_*D_)      // 2048 — decoder N (both layers fused)
#define SPLITK 8
#define KC  (F_/SPLITK)  // 4096 per split-K chunk

// Tile config
#define BM 128
#define BN 128
#define BK 64
#define KT1 (K1/BK)      // 32 k-tiles for GEMM1
#define KT2 (F_/BK)      // 512 k-tiles for GEMM2
#define NTK (KT2/SPLITK) // 64 k-tiles per split
#define TILE_E 8192      // elements per 16KB image (128 rows x 64 k)

typedef __attribute__((ext_vector_type(4))) float  f32x4;
typedef __attribute__((ext_vector_type(8))) __bf16 bf16x8;

__device__ inline void glds16(const void* g, void* l) {
    __builtin_amdgcn_global_load_lds(
        (const __attribute__((address_space(1))) unsigned int*)g,
        (__attribute__((address_space(3))) unsigned int*)l, 16, 0, 0);
}

// Image layout (16 KB per (panel, k-tile)): element index =
//   row*64 + ((chunk ^ (row&7))<<3) + off   where chunk=k>>3, off=k&7
// XOR bakes the bank-conflict swizzle into global memory so glds stays linear
// (rule #21: linear LDS dest + inverse-swizzled source + swizzled read).

// ---------------------------------------------------------------------------
// Prepass: x [M][K1] fp32 row-major -> A-images (no transpose)
// ---------------------------------------------------------------------------
__global__ __launch_bounds__(256) void conv_x(
    const float* __restrict__ X, __bf16* __restrict__ Xb)
{
    const int img = blockIdx.x;          // mp*KT1 + t, grid 8*32=256
    const int mp = img / KT1, t = img % KT1;
    const int tid = threadIdx.x;
    const int row = tid >> 1, half = tid & 1;
    const float* src = X + ((size_t)(mp*128 + row))*K1 + t*64 + half*32;
    __bf16* dst = Xb + (size_t)img * TILE_E;
    #pragma unroll
    for (int cc = 0; cc < 4; ++cc) {
        int c = half*4 + cc;
        f32x4 u = *(const f32x4*)(src + cc*8);
        f32x4 v = *(const f32x4*)(src + cc*8 + 4);
        bf16x8 o;
        #pragma unroll
        for (int e = 0; e < 4; ++e) { o[e] = (__bf16)u[e]; o[e+4] = (__bf16)v[e]; }
        *(bf16x8*)&dst[row*64 + ((c ^ (row&7))<<3)] = o;
    }
}

// ---------------------------------------------------------------------------
// Prepass: W [K][N] fp32 (N contiguous) -> transposed B-images [n-row][k]
// One block per 16KB image. Each thread owns one n-row for 4 chunks: gathers
// 8 k-strided f32 (coalesced across lanes: consecutive n), packs bf16x8,
// single ds_write_b128 (uniform 8-group bank spread = conflict-free).
// Writeback: chunk w = v*256+tid -> LDS reads conflict-free, global 4KB/instr.
// ---------------------------------------------------------------------------
__global__ __launch_bounds__(256) void conv_bt(
    const float* __restrict__ S, __bf16* __restrict__ Dst,
    int KT, int strideK, int NL, long long strideL)
{
    __shared__ __bf16 lds[TILE_E];
    const int img = blockIdx.x;
    const int p = img / KT, t = img % KT;
    const int tid = threadIdx.x;
    const int n0 = p * 128;
    const int k0 = t * 64;
    const int row = tid & 127;
    const int half = tid >> 7;           // chunk group: 0 -> c=0..3, 1 -> c=4..7
    const float* base = S + (size_t)(n0 / NL) * (size_t)strideL + (n0 % NL) + row;
    #pragma unroll
    for (int cc = 0; cc < 4; ++cc) {
        int c = half*4 + cc;
        bf16x8 o;
        #pragma unroll
        for (int off = 0; off < 8; ++off)
            o[off] = (__bf16)base[(size_t)(k0 + c*8 + off) * strideK];
        *(bf16x8*)&lds[row*64 + ((c ^ (row&7))<<3)] = o;
    }
    __syncthreads();
    char* out = (char*)(Dst + (size_t)img * TILE_E);
    const char* lc = (const char*)lds;
    #pragma unroll
    for (int v = 0; v < 4; ++v)
        *(f32x4*)(out + v*4096 + tid*16) = *(const f32x4*)(lc + v*4096 + tid*16);
}

// ---------------------------------------------------------------------------
// GEMM1: f = relu(x @ W_enc + b_enc); all-glds K-loop; writes f in image layout
// ---------------------------------------------------------------------------
__global__ __launch_bounds__(256, 3) void gemm1_enc(
    const __bf16* __restrict__ Ax, const __bf16* __restrict__ Bw,
    const float* __restrict__ be, __bf16* __restrict__ Fimg)
{
    __shared__ __bf16 As[TILE_E];
    __shared__ __bf16 Bs[TILE_E];

    const int bid = blockIdx.x;          // 0..2047
    const int xcd = bid & 7;
    const int j   = bid >> 3;            // 0..255
    const int mp  = j & 7;
    const int np  = xcd*32 + (j >> 3);   // XCD owns 32 consecutive n-panels
    const int n0  = np * BN;

    const int tid = threadIdx.x;
    const int lane = tid & 63;
    const int w  = tid >> 6;
    const int wr = w >> 1, wc = w & 1;
    const int g  = lane >> 4;
    const int r  = lane & 15;

    const __bf16* pa = Ax + (size_t)mp * KT1 * TILE_E;
    const __bf16* pb = Bw + (size_t)np * KT1 * TILE_E;

    f32x4 acc[4][4] = {};

    int aOff[2][4], bOff[2][4];
    #pragma unroll
    for (int kk = 0; kk < 2; ++kk)
        #pragma unroll
        for (int i = 0; i < 4; ++i) {
            int rowA = wr*64 + i*16 + r;
            aOff[kk][i] = rowA*64 + (((kk*4 + g) ^ (rowA&7))<<3);
            int rowB = wc*64 + i*16 + r;
            bOff[kk][i] = rowB*64 + (((kk*4 + g) ^ (rowB&7))<<3);
        }

    for (int t = 0; t < KT1; ++t) {
        const char* sa = (const char*)(pa + (size_t)t * TILE_E);
        const char* sb = (const char*)(pb + (size_t)t * TILE_E);
        #pragma unroll
        for (int q = 0; q < 4; ++q) {
            glds16(sa + q*4096 + tid*16, (char*)As + q*4096 + tid*16);
            glds16(sb + q*4096 + tid*16, (char*)Bs + q*4096 + tid*16);
        }
        __syncthreads();                 // drains vmcnt (glds) for all waves
        #pragma unroll
        for (int kk = 0; kk < 2; ++kk) {
            bf16x8 a[4], b[4];
            #pragma unroll
            for (int i = 0; i < 4; ++i) a[i] = *(const bf16x8*)&As[aOff[kk][i]];
            #pragma unroll
            for (int jj = 0; jj < 4; ++jj) b[jj] = *(const bf16x8*)&Bs[bOff[kk][jj]];
            #pragma unroll
            for (int i = 0; i < 4; ++i)
                #pragma unroll
                for (int jj = 0; jj < 4; ++jj)
                    acc[i][jj] = __builtin_amdgcn_mfma_f32_16x16x32_bf16(
                        a[i], b[jj], acc[i][jj], 0, 0, 0);
        }
        __syncthreads();
    }

    // epilogue: relu(acc + b_enc) -> f stored as GEMM2 A-images
    #pragma unroll
    for (int jj = 0; jj < 4; ++jj) {
        int col = n0 + wc*64 + jj*16 + r;     // global f index (GEMM2 k)
        float bv = be[col];
        int t  = col >> 6;                    // which image
        int c  = (col & 63) >> 3;
        int off = col & 7;
        __bf16* base = Fimg + ((size_t)mp * KT2 + t) * TILE_E;
        #pragma unroll
        for (int i = 0; i < 4; ++i)
            #pragma unroll
            for (int v = 0; v < 4; ++v) {
                int lrow = wr*64 + i*16 + g*4 + v;
                float z = acc[i][jj][v] + bv;
                z = z > 0.f ? z : 0.f;
                base[lrow*64 + ((c ^ (lrow&7))<<3) + off] = (__bf16)z;
            }
    }
}

// ---------------------------------------------------------------------------
// GEMM2 (split-K=8): Cp[s] = f-chunk @ W_dec-chunk; both operands glds images
// ---------------------------------------------------------------------------
__global__ __launch_bounds__(256, 3) void gemm2_dec(
    const __bf16* __restrict__ Fimg, const __bf16* __restrict__ Bw,
    float* __restrict__ Cp)
{
    __shared__ __bf16 As[TILE_E];
    __shared__ __bf16 Bs[TILE_E];

    const int bid = blockIdx.x;          // 0..1023
    const int xcd = bid & 7;
    const int j   = bid >> 3;            // 0..127
    const int mp  = j & 7;
    const int pair = xcd*16 + (j >> 3);  // 0..127
    const int s   = pair & 7;
    const int np  = pair >> 3;           // 0..15
    const int n0  = np * BN;
    const int m0  = mp * BM;

    const int tid = threadIdx.x;
    const int lane = tid & 63;
    const int w  = tid >> 6;
    const int wr = w >> 1, wc = w & 1;
    const int g  = lane >> 4;
    const int r  = lane & 15;

    const __bf16* pa = Fimg + ((size_t)mp * KT2 + s * NTK) * TILE_E;
    const __bf16* pb = Bw   + ((size_t)np * KT2 + s * NTK) * TILE_E;

    f32x4 acc[4][4] = {};

    int aOff[2][4], bOff[2][4];
    #pragma unroll
    for (int kk = 0; kk < 2; ++kk)
        #pragma unroll
        for (int i = 0; i < 4; ++i) {
            int rowA = wr*64 + i*16 + r;
            aOff[kk][i] = rowA*64 + (((kk*4 + g) ^ (rowA&7))<<3);
            int rowB = wc*64 + i*16 + r;
            bOff[kk][i] = rowB*64 + (((kk*4 + g) ^ (rowB&7))<<3);
        }

    for (int t = 0; t < NTK; ++t) {
        const char* sa = (const char*)(pa + (size_t)t * TILE_E);
        const char* sb = (const char*)(pb + (size_t)t * TILE_E);
        #pragma unroll
        for (int q = 0; q < 4; ++q) {
            glds16(sa + q*4096 + tid*16, (char*)As + q*4096 + tid*16);
            glds16(sb + q*4096 + tid*16, (char*)Bs + q*4096 + tid*16);
        }
        __syncthreads();
        #pragma unroll
        for (int kk = 0; kk < 2; ++kk) {
            bf16x8 a[4], b[4];
            #pragma unroll
            for (int i = 0; i < 4; ++i) a[i] = *(const bf16x8*)&As[aOff[kk][i]];
            #pragma unroll
            for (int jj = 0; jj < 4; ++jj) b[jj] = *(const bf16x8*)&Bs[bOff[kk][jj]];
            #pragma unroll
            for (int i = 0; i < 4; ++i)
                #pragma unroll
                for (int jj = 0; jj < 4; ++jj)
                    acc[i][jj] = __builtin_amdgcn_mfma_f32_16x16x32_bf16(
                        a[i], b[jj], acc[i][jj], 0, 0, 0);
        }
        __syncthreads();
    }

    #pragma unroll
    for (int jj = 0; jj < 4; ++jj) {
        int col = n0 + wc*64 + jj*16 + r;
        #pragma unroll
        for (int i = 0; i < 4; ++i)
            #pragma unroll
            for (int v = 0; v < 4; ++v) {
                int row = m0 + wr*64 + i*16 + g*4 + v;
                Cp[((size_t)s*M_ + row)*N2 + col] = acc[i][jj][v];
            }
    }
}

// ---------------------------------------------------------------------------
// Reduce: out[m][n] = sum_s Cp[s][m][n] + b_dec[n]
// ---------------------------------------------------------------------------
__global__ __launch_bounds__(256) void reduce_add(
    const float* __restrict__ Cp, const float* __restrict__ bd,
    float* __restrict__ out)
{
    const size_t idx = ((size_t)blockIdx.x * 256 + threadIdx.x) * 4;
    f32x4 acc = {};
    #pragma unroll
    for (int s = 0; s < SPLITK; ++s) {
        f32x4 c = *(const f32x4*)(Cp + (size_t)s * M_ * N2 + idx);
        acc += c;
    }
    f32x4 b = *(const f32x4*)(bd + (idx & (N2 - 1)));
    *(f32x4*)(out + idx) = acc + b;
}

// ---------------------------------------------------------------------------
extern "C" void kernel_launch(void* const* d_in, const int* in_sizes, int n_in,
                              void* d_out, int out_size, void* d_ws, size_t ws_size,
                              hipStream_t stream) {
    const float* x  = (const float*)d_in[0];
    const float* We = (const float*)d_in[1];
    const float* be = (const float*)d_in[2];
    const float* Wd = (const float*)d_in[3];
    const float* bd = (const float*)d_in[4];
    float* out = (float*)d_out;

    // ws layout (256 MB total, time-multiplexed):
    //   fB @ 0      : 64 MB   f images (bf16)
    //   WB @ 64 MB  : 128 MB  weight images — first W_enc, then overwritten by
    //                         W_dec after gemm1 (W_enc images dead by then)
    //   Cp @ 192 MB : 64 MB   split-K partials (fp32)
    //   xB = head of Cp region (4 MB) — dead before gemm2 writes Cp
    char* wsb = (char*)d_ws;
    __bf16* fB = (__bf16*)(wsb);
    __bf16* WB = (__bf16*)(wsb + (size_t)64*1024*1024);
    float*  Cp = (float*)(wsb + (size_t)192*1024*1024);
    __bf16* xB = (__bf16*)Cp;

    conv_x<<<dim3(8*KT1), 256, 0, stream>>>(x, xB);
    conv_bt<<<dim3(256*KT1), 256, 0, stream>>>(We, WB, KT1, F_, F_, 0LL);
    gemm1_enc<<<dim3((M_/BM)*(F_/BN)), 256, 0, stream>>>(xB, WB, be, fB);
    conv_bt<<<dim3(16*KT2), 256, 0, stream>>>(Wd, WB, KT2, D_, D_,
                                              (long long)F_*D_);
    gemm2_dec<<<dim3((M_/BM)*(N2/BN)*SPLITK), 256, 0, stream>>>(fB, WB, Cp);
    reduce_add<<<dim3((M_*(size_t)N2)/(4*256)), 256, 0, stream>>>(Cp, bd, out);
}